// Round 3
// baseline (586.412 us; speedup 1.0000x reference)
//
#include <hip/hip_runtime.h>

#define B_ 2
#define N_ 4096
#define M_ 32
#define D_ 128
#define E_ 64
#define LN_EPS 1e-5f
#define WST 136              // bf16 elems/row of w-tile: 272B rows, 16B-aligned
#define TOT (B_ * N_)
#define FGRID 1536           // 6 blocks/CU * 256 CU: LDS 6*25.5KB=153KB fits,
                             // VGPR 84 <= 512/6=85 fits. Doubles the round-0 TLP.

typedef __bf16 bf16x8 __attribute__((ext_vector_type(8)));
typedef float  f32x4  __attribute__((ext_vector_type(4)));

// ---------------------------------------------------------------------------
// K1: projections. One wave per bn (4 bn / 256-thr block). x staged in LDS
// packed [d][8] so the d-loop does 2 broadcast ds_read_b128 instead of 8
// scalar loads. q stored fp32 [bn][e][8]; k stored bf16 [bn][e][8].
// Slots: 0..2 = x1(ml0..2), 3..7 = x2(ml0..4).
// ---------------------------------------------------------------------------
__global__ __launch_bounds__(256) void proj_kernel(
    const float* __restrict__ x1, const float* __restrict__ x2,
    const float* __restrict__ Wq, const float* __restrict__ Wk1,
    const float* __restrict__ Wk2,
    float* __restrict__ qws, __bf16* __restrict__ kws)
{
    __shared__ float xs[4][D_ * 8];
    const int lane = threadIdx.x & 63;
    const int wv   = threadIdx.x >> 6;
    const int bn   = blockIdx.x * 4 + wv;
    float* xw = xs[wv];
    const float* __restrict__ x1p = x1 + (size_t)bn * (D_ * 3);
    const float* __restrict__ x2p = x2 + (size_t)bn * (D_ * 5);
    for (int i = lane; i < D_ * 3; i += 64) xw[(i / 3) * 8 + (i % 3)]     = x1p[i];
    for (int i = lane; i < D_ * 5; i += 64) xw[(i / 5) * 8 + 3 + (i % 5)] = x2p[i];
    __syncthreads();

    float q[8] = {0.f,0.f,0.f,0.f,0.f,0.f,0.f,0.f};
    float k[8] = {0.f,0.f,0.f,0.f,0.f,0.f,0.f,0.f};
    #pragma unroll 4
    for (int d = 0; d < D_; ++d) {
        const float4 xa = *(const float4*)&xw[d * 8];       // broadcast b128
        const float4 xb = *(const float4*)&xw[d * 8 + 4];
        const float wq  = Wq [d * E_ + lane];
        const float wk1 = Wk1[d * E_ + lane];
        const float wk2 = Wk2[d * E_ + lane];
        q[0] += xa.x * wq;  q[1] += xa.y * wq;  q[2] += xa.z * wq;  q[3] += xa.w * wq;
        q[4] += xb.x * wq;  q[5] += xb.y * wq;  q[6] += xb.z * wq;  q[7] += xb.w * wq;
        k[0] += xa.x * wk1; k[1] += xa.y * wk1; k[2] += xa.z * wk1;
        k[3] += xa.w * wk2; k[4] += xb.x * wk2; k[5] += xb.y * wk2;
        k[6] += xb.z * wk2; k[7] += xb.w * wk2;
    }
    float4* qo = (float4*)(qws + ((size_t)bn * E_ + lane) * 8);
    qo[0] = make_float4(q[0], q[1], q[2], q[3]);
    qo[1] = make_float4(q[4], q[5], q[6], q[7]);
    bf16x8 kb;
    #pragma unroll
    for (int s = 0; s < 8; ++s) kb[s] = (__bf16)k[s];
    *(bf16x8*)(kws + ((size_t)bn * E_ + lane) * 8) = kb;
}

// ---------------------------------------------------------------------------
// K2: fused gather + LN + dual MFMA matmul + epilogue.
// ROUND-0 BODY UNCHANGED (proven 159 us @ 3 blocks/CU, no spills, VGPR 84).
// Round-1/2 lesson: with bE/bR (64 VGPR) persistent there is no register
// budget for a deeper in-register prefetch pipeline -- round 2's attempt
// spilled to scratch (+194 MB FETCH). The stall is latency with only 3
// correlated-stall waves per SIMD (VALUBusy 27% ~= 3 x per-wave duty).
// Fix: DOUBLE RESIDENCY. 26112 B LDS -> 6 blocks/CU fit (153/160 KB);
// VGPR 84 <= 512/6 = 85 -> 6 waves/SIMD fit. Grid 1536, bounds (256,6).
// Pipeline per bn: phaseW(next) -> barrier -> phaseM(curr) -> tload(next).
// Triple buffer + single barrier is race-free: a write to buffer X in iter
// i+3k is separated from the prior read of X by >=1 full-block barrier.
// ---------------------------------------------------------------------------
__global__ __launch_bounds__(256, 6) void fused_kernel(
    const float* __restrict__ t_ij, const int* __restrict__ nidx,
    const float* __restrict__ qws, const __bf16* __restrict__ kws,
    const float* __restrict__ ln_w,
    const float* __restrict__ edge_w, const float* __restrict__ res_w,
    float* __restrict__ out)
{
    __shared__ __bf16 wbuf[3][M_ * WST];

    const int t    = threadIdx.x;
    const int lane = t & 63;
    const int wvu  = t >> 6;
    const int r16  = lane & 15;
    const int quad = lane >> 4;
    const int n0   = wvu * 32;          // this wave's 32-col output slice

    // ---- persistent B-fragments (fp32 global -> bf16 regs), one-time ----
    // B[k][n]: lane holds k = ks*32 + quad*8 + j, n = n0 + nt*16 + r16.
    bf16x8 bE[2][4], bR[2][4];
    #pragma unroll
    for (int nt = 0; nt < 2; ++nt) {
        const int col = n0 + nt * 16 + r16;
        #pragma unroll
        for (int ks = 0; ks < 4; ++ks) {
            const int k0 = ks * 32 + quad * 8;
            bf16x8 fe, fr;
            #pragma unroll
            for (int j = 0; j < 8; ++j) {
                fe[j] = (__bf16)edge_w[(k0 + j) * D_ + col];
                fr[j] = (__bf16)res_w [(k0 + j) * D_ + col];
            }
            bE[nt][ks] = fe;
            bR[nt][ks] = fr;
        }
    }

    const float lnlo = ln_w[lane];
    const float lnhi = ln_w[64 + lane];

    // ---- phase W: compute+LN 8 j-rows of w into an LDS buffer ----
    auto phaseW = [&](int bn, __bf16* buf) {
        const int    b  = bn >> 12;
        const size_t jb = (size_t)bn * M_;
        const float* qp = qws + ((size_t)bn * E_ + lane) * 8;
        const float4 qa = *(const float4*)qp;
        const float4 qb = *(const float4*)(qp + 4);
        #pragma unroll 4
        for (int jj = 0; jj < 8; ++jj) {
            const int j  = wvu * 8 + jj;
            const int nj = nidx[jb + j];
            const bf16x8 kv =
                *(const bf16x8*)&kws[((size_t)(b * N_ + nj) * E_ + lane) * 8];
            const float wlo = qa.x * (float)kv[0] + qa.y * (float)kv[1]
                            + qa.z * (float)kv[2];
            const float whi = qa.w * (float)kv[3] + qb.x * (float)kv[4]
                            + qb.y * (float)kv[5] + qb.z * (float)kv[6]
                            + qb.w * (float)kv[7];
            float s1 = wlo + whi;
            float s2 = wlo * wlo + whi * whi;
            #pragma unroll
            for (int off = 1; off < 64; off <<= 1) {
                s1 += __shfl_xor(s1, off, 64);
                s2 += __shfl_xor(s2, off, 64);
            }
            const float mu  = s1 * (1.f / 128.f);
            const float var = fmaxf(s2 * (1.f / 128.f) - mu * mu, 0.f);
            const float rs  = rsqrtf(var + LN_EPS);
            buf[j * WST + lane]      = (__bf16)((wlo - mu) * rs * lnlo);
            buf[j * WST + 64 + lane] = (__bf16)((whi - mu) * rs * lnhi);
        }
    };

    // ---- t_ij prefetch for mt=0 rows (r16), packed to bf16 A-frags ----
    auto tload = [&](int bn, bf16x8* tf) {
        const float* tp = t_ij + ((size_t)bn * M_ + r16) * D_;
        #pragma unroll
        for (int ks = 0; ks < 4; ++ks) {
            const int ko = ks * 32 + quad * 8;
            const float4 t0 = *(const float4*)(tp + ko);
            const float4 t1 = *(const float4*)(tp + ko + 4);
            bf16x8 a;
            a[0]=(__bf16)t0.x; a[1]=(__bf16)t0.y; a[2]=(__bf16)t0.z; a[3]=(__bf16)t0.w;
            a[4]=(__bf16)t1.x; a[5]=(__bf16)t1.y; a[6]=(__bf16)t1.z; a[7]=(__bf16)t1.w;
            tf[ks] = a;
        }
    };

    // ---- phase M: dual matmul for this wave's 32 cols + fused epilogue ----
    auto phaseM = [&](int bn, const __bf16* buf, const bf16x8* tf) {
        const size_t jb = (size_t)bn * M_;
        // mt=1 t_ij rows: load + convert immediately (keeps VGPR low)
        bf16x8 aT1[4];
        {
            const float* tp = t_ij + (jb + 16 + r16) * D_;
            #pragma unroll
            for (int ks = 0; ks < 4; ++ks) {
                const int ko = ks * 32 + quad * 8;
                const float4 t0 = *(const float4*)(tp + ko);
                const float4 t1 = *(const float4*)(tp + ko + 4);
                bf16x8 a;
                a[0]=(__bf16)t0.x; a[1]=(__bf16)t0.y; a[2]=(__bf16)t0.z; a[3]=(__bf16)t0.w;
                a[4]=(__bf16)t1.x; a[5]=(__bf16)t1.y; a[6]=(__bf16)t1.z; a[7]=(__bf16)t1.w;
                aT1[ks] = a;
            }
        }
        f32x4 accE[2][2], accR[2][2];
        #pragma unroll
        for (int mt = 0; mt < 2; ++mt)
            #pragma unroll
            for (int nt = 0; nt < 2; ++nt) {
                accE[mt][nt] = (f32x4){0.f,0.f,0.f,0.f};
                accR[mt][nt] = (f32x4){0.f,0.f,0.f,0.f};
            }
        #pragma unroll
        for (int ks = 0; ks < 4; ++ks) {
            const bf16x8 aW0 = *(const bf16x8*)&buf[r16 * WST + ks * 32 + quad * 8];
            const bf16x8 aW1 = *(const bf16x8*)&buf[(16 + r16) * WST + ks * 32 + quad * 8];
            #pragma unroll
            for (int nt = 0; nt < 2; ++nt) {
                accE[0][nt] = __builtin_amdgcn_mfma_f32_16x16x32_bf16(aW0,    bE[nt][ks], accE[0][nt], 0, 0, 0);
                accR[0][nt] = __builtin_amdgcn_mfma_f32_16x16x32_bf16(tf[ks], bR[nt][ks], accR[0][nt], 0, 0, 0);
                accE[1][nt] = __builtin_amdgcn_mfma_f32_16x16x32_bf16(aW1,    bE[nt][ks], accE[1][nt], 0, 0, 0);
                accR[1][nt] = __builtin_amdgcn_mfma_f32_16x16x32_bf16(aT1[ks],bR[nt][ks], accR[1][nt], 0, 0, 0);
            }
        }
        // epilogue: sigmoid(edge) + res, store fp32
        #pragma unroll
        for (int mt = 0; mt < 2; ++mt)
            #pragma unroll
            for (int nt = 0; nt < 2; ++nt)
                #pragma unroll
                for (int rr = 0; rr < 4; ++rr) {
                    const int row = mt * 16 + quad * 4 + rr;
                    const int col = n0 + nt * 16 + r16;
                    const float e  = accE[mt][nt][rr];
                    const float sg = 1.f / (1.f + __expf(-e));
                    out[(jb + row) * D_ + col] = sg + accR[mt][nt][rr];
                }
    };

    // ---- main pipeline: W(next) -> barrier -> M(curr) -> tload(next) ----
    const int stride = gridDim.x;
    int bn = blockIdx.x;
    bf16x8 tf[4];
    phaseW(bn, wbuf[0]);
    tload(bn, tf);
    int buf = 0;
    for (; bn < TOT; bn += stride) {
        const int nb   = bn + stride;
        const int nbuf = (buf == 2) ? 0 : buf + 1;
        if (nb < TOT) phaseW(nb, wbuf[nbuf]);
        __syncthreads();
        phaseM(bn, wbuf[buf], tf);
        if (nb < TOT) tload(nb, tf);
        buf = nbuf;
    }
}

extern "C" void kernel_launch(void* const* d_in, const int* in_sizes, int n_in,
                              void* d_out, int out_size, void* d_ws, size_t ws_size,
                              hipStream_t stream) {
    const float* t_ij = (const float*)d_in[0];
    const float* x1   = (const float*)d_in[1];
    const float* x2   = (const float*)d_in[2];
    const int*   nidx = (const int*)  d_in[3];
    const float* Wq   = (const float*)d_in[4];
    const float* Wk1  = (const float*)d_in[5];
    const float* Wk2  = (const float*)d_in[6];
    const float* lnw  = (const float*)d_in[7];
    const float* eww  = (const float*)d_in[8];
    const float* rww  = (const float*)d_in[9];
    float* out = (float*)d_out;

    // ws layout: qws fp32 [bn][e][8] (16.78 MB) | kws bf16 [bn][e][8] (8.39 MB)
    float*  qws = (float*)d_ws;
    __bf16* kws = (__bf16*)(qws + (size_t)TOT * E_ * 8);

    proj_kernel<<<TOT / 4, 256, 0, stream>>>(x1, x2, Wq, Wk1, Wk2, qws, kws);
    fused_kernel<<<FGRID, 256, 0, stream>>>(t_ij, nidx, qws, kws, lnw, eww, rww, out);
}

// Round 4
// 394.344 us; speedup vs baseline: 1.4871x; 1.4871x over previous
//
#include <hip/hip_runtime.h>

#define B_ 2
#define N_ 4096
#define M_ 32
#define D_ 128
#define E_ 64
#define LN_EPS 1e-5f
#define WST 136              // bf16 elems/row of w-tile: 272B rows, 16B-aligned
#define TOT (B_ * N_)
#define FGRID 1536           // 6 blocks/CU residency. NOTE: launch_bounds stays
                             // (256,3) -- round-3 lesson: raising the min-waves
                             // hint to 6 made the compiler cut VGPR 84->40 and
                             // spill bE/bR (+828 MB scratch traffic). Residency
                             // is set by ACTUAL resources (VGPR 84 -> 6 wv/SIMD,
                             // LDS 25.5KB -> 6 blk/CU); only the grid was short.

typedef __bf16 bf16x8 __attribute__((ext_vector_type(8)));
typedef float  f32x4  __attribute__((ext_vector_type(4)));

// ---------------------------------------------------------------------------
// K1: projections. One wave per bn (4 bn / 256-thr block). x staged in LDS
// packed [d][8] so the d-loop does 2 broadcast ds_read_b128 instead of 8
// scalar loads. q stored fp32 [bn][e][8]; k stored bf16 [bn][e][8].
// Slots: 0..2 = x1(ml0..2), 3..7 = x2(ml0..4).
// ---------------------------------------------------------------------------
__global__ __launch_bounds__(256) void proj_kernel(
    const float* __restrict__ x1, const float* __restrict__ x2,
    const float* __restrict__ Wq, const float* __restrict__ Wk1,
    const float* __restrict__ Wk2,
    float* __restrict__ qws, __bf16* __restrict__ kws)
{
    __shared__ float xs[4][D_ * 8];
    const int lane = threadIdx.x & 63;
    const int wv   = threadIdx.x >> 6;
    const int bn   = blockIdx.x * 4 + wv;
    float* xw = xs[wv];
    const float* __restrict__ x1p = x1 + (size_t)bn * (D_ * 3);
    const float* __restrict__ x2p = x2 + (size_t)bn * (D_ * 5);
    for (int i = lane; i < D_ * 3; i += 64) xw[(i / 3) * 8 + (i % 3)]     = x1p[i];
    for (int i = lane; i < D_ * 5; i += 64) xw[(i / 5) * 8 + 3 + (i % 5)] = x2p[i];
    __syncthreads();

    float q[8] = {0.f,0.f,0.f,0.f,0.f,0.f,0.f,0.f};
    float k[8] = {0.f,0.f,0.f,0.f,0.f,0.f,0.f,0.f};
    #pragma unroll 4
    for (int d = 0; d < D_; ++d) {
        const float4 xa = *(const float4*)&xw[d * 8];       // broadcast b128
        const float4 xb = *(const float4*)&xw[d * 8 + 4];
        const float wq  = Wq [d * E_ + lane];
        const float wk1 = Wk1[d * E_ + lane];
        const float wk2 = Wk2[d * E_ + lane];
        q[0] += xa.x * wq;  q[1] += xa.y * wq;  q[2] += xa.z * wq;  q[3] += xa.w * wq;
        q[4] += xb.x * wq;  q[5] += xb.y * wq;  q[6] += xb.z * wq;  q[7] += xb.w * wq;
        k[0] += xa.x * wk1; k[1] += xa.y * wk1; k[2] += xa.z * wk1;
        k[3] += xa.w * wk2; k[4] += xb.x * wk2; k[5] += xb.y * wk2;
        k[6] += xb.z * wk2; k[7] += xb.w * wk2;
    }
    float4* qo = (float4*)(qws + ((size_t)bn * E_ + lane) * 8);
    qo[0] = make_float4(q[0], q[1], q[2], q[3]);
    qo[1] = make_float4(q[4], q[5], q[6], q[7]);
    bf16x8 kb;
    #pragma unroll
    for (int s = 0; s < 8; ++s) kb[s] = (__bf16)k[s];
    *(bf16x8*)(kws + ((size_t)bn * E_ + lane) * 8) = kb;
}

// ---------------------------------------------------------------------------
// K2: fused gather + LN + dual MFMA matmul + epilogue.
// BODY IDENTICAL to the proven 159us round-0 kernel (VGPR 84, no spills).
// Only the grid changed: 768 -> 1536 so the runtime packs 6 blocks/CU
// (doubling the independent stall chains per SIMD; the kernel is
// latency-bound: VALUBusy 27% @ 3 blk/CU with HBM at only 23%).
// Pipeline per bn: phaseW(next) -> barrier -> phaseM(curr) -> tload(next).
// Triple buffer + single barrier is race-free: a write to buffer X in iter
// i+3k is separated from the prior read of X by >=1 full-block barrier.
// ---------------------------------------------------------------------------
__global__ __launch_bounds__(256, 3) void fused_kernel(
    const float* __restrict__ t_ij, const int* __restrict__ nidx,
    const float* __restrict__ qws, const __bf16* __restrict__ kws,
    const float* __restrict__ ln_w,
    const float* __restrict__ edge_w, const float* __restrict__ res_w,
    float* __restrict__ out)
{
    __shared__ __bf16 wbuf[3][M_ * WST];

    const int t    = threadIdx.x;
    const int lane = t & 63;
    const int wvu  = t >> 6;
    const int r16  = lane & 15;
    const int quad = lane >> 4;
    const int n0   = wvu * 32;          // this wave's 32-col output slice

    // ---- persistent B-fragments (fp32 global -> bf16 regs), one-time ----
    // B[k][n]: lane holds k = ks*32 + quad*8 + j, n = n0 + nt*16 + r16.
    bf16x8 bE[2][4], bR[2][4];
    #pragma unroll
    for (int nt = 0; nt < 2; ++nt) {
        const int col = n0 + nt * 16 + r16;
        #pragma unroll
        for (int ks = 0; ks < 4; ++ks) {
            const int k0 = ks * 32 + quad * 8;
            bf16x8 fe, fr;
            #pragma unroll
            for (int j = 0; j < 8; ++j) {
                fe[j] = (__bf16)edge_w[(k0 + j) * D_ + col];
                fr[j] = (__bf16)res_w [(k0 + j) * D_ + col];
            }
            bE[nt][ks] = fe;
            bR[nt][ks] = fr;
        }
    }

    const float lnlo = ln_w[lane];
    const float lnhi = ln_w[64 + lane];

    // ---- phase W: compute+LN 8 j-rows of w into an LDS buffer ----
    auto phaseW = [&](int bn, __bf16* buf) {
        const int    b  = bn >> 12;
        const size_t jb = (size_t)bn * M_;
        const float* qp = qws + ((size_t)bn * E_ + lane) * 8;
        const float4 qa = *(const float4*)qp;
        const float4 qb = *(const float4*)(qp + 4);
        #pragma unroll 4
        for (int jj = 0; jj < 8; ++jj) {
            const int j  = wvu * 8 + jj;
            const int nj = nidx[jb + j];
            const bf16x8 kv =
                *(const bf16x8*)&kws[((size_t)(b * N_ + nj) * E_ + lane) * 8];
            const float wlo = qa.x * (float)kv[0] + qa.y * (float)kv[1]
                            + qa.z * (float)kv[2];
            const float whi = qa.w * (float)kv[3] + qb.x * (float)kv[4]
                            + qb.y * (float)kv[5] + qb.z * (float)kv[6]
                            + qb.w * (float)kv[7];
            float s1 = wlo + whi;
            float s2 = wlo * wlo + whi * whi;
            #pragma unroll
            for (int off = 1; off < 64; off <<= 1) {
                s1 += __shfl_xor(s1, off, 64);
                s2 += __shfl_xor(s2, off, 64);
            }
            const float mu  = s1 * (1.f / 128.f);
            const float var = fmaxf(s2 * (1.f / 128.f) - mu * mu, 0.f);
            const float rs  = rsqrtf(var + LN_EPS);
            buf[j * WST + lane]      = (__bf16)((wlo - mu) * rs * lnlo);
            buf[j * WST + 64 + lane] = (__bf16)((whi - mu) * rs * lnhi);
        }
    };

    // ---- t_ij prefetch for mt=0 rows (r16), packed to bf16 A-frags ----
    auto tload = [&](int bn, bf16x8* tf) {
        const float* tp = t_ij + ((size_t)bn * M_ + r16) * D_;
        #pragma unroll
        for (int ks = 0; ks < 4; ++ks) {
            const int ko = ks * 32 + quad * 8;
            const float4 t0 = *(const float4*)(tp + ko);
            const float4 t1 = *(const float4*)(tp + ko + 4);
            bf16x8 a;
            a[0]=(__bf16)t0.x; a[1]=(__bf16)t0.y; a[2]=(__bf16)t0.z; a[3]=(__bf16)t0.w;
            a[4]=(__bf16)t1.x; a[5]=(__bf16)t1.y; a[6]=(__bf16)t1.z; a[7]=(__bf16)t1.w;
            tf[ks] = a;
        }
    };

    // ---- phase M: dual matmul for this wave's 32 cols + fused epilogue ----
    auto phaseM = [&](int bn, const __bf16* buf, const bf16x8* tf) {
        const size_t jb = (size_t)bn * M_;
        // mt=1 t_ij rows: load + convert immediately (keeps VGPR low)
        bf16x8 aT1[4];
        {
            const float* tp = t_ij + (jb + 16 + r16) * D_;
            #pragma unroll
            for (int ks = 0; ks < 4; ++ks) {
                const int ko = ks * 32 + quad * 8;
                const float4 t0 = *(const float4*)(tp + ko);
                const float4 t1 = *(const float4*)(tp + ko + 4);
                bf16x8 a;
                a[0]=(__bf16)t0.x; a[1]=(__bf16)t0.y; a[2]=(__bf16)t0.z; a[3]=(__bf16)t0.w;
                a[4]=(__bf16)t1.x; a[5]=(__bf16)t1.y; a[6]=(__bf16)t1.z; a[7]=(__bf16)t1.w;
                aT1[ks] = a;
            }
        }
        f32x4 accE[2][2], accR[2][2];
        #pragma unroll
        for (int mt = 0; mt < 2; ++mt)
            #pragma unroll
            for (int nt = 0; nt < 2; ++nt) {
                accE[mt][nt] = (f32x4){0.f,0.f,0.f,0.f};
                accR[mt][nt] = (f32x4){0.f,0.f,0.f,0.f};
            }
        #pragma unroll
        for (int ks = 0; ks < 4; ++ks) {
            const bf16x8 aW0 = *(const bf16x8*)&buf[r16 * WST + ks * 32 + quad * 8];
            const bf16x8 aW1 = *(const bf16x8*)&buf[(16 + r16) * WST + ks * 32 + quad * 8];
            #pragma unroll
            for (int nt = 0; nt < 2; ++nt) {
                accE[0][nt] = __builtin_amdgcn_mfma_f32_16x16x32_bf16(aW0,    bE[nt][ks], accE[0][nt], 0, 0, 0);
                accR[0][nt] = __builtin_amdgcn_mfma_f32_16x16x32_bf16(tf[ks], bR[nt][ks], accR[0][nt], 0, 0, 0);
                accE[1][nt] = __builtin_amdgcn_mfma_f32_16x16x32_bf16(aW1,    bE[nt][ks], accE[1][nt], 0, 0, 0);
                accR[1][nt] = __builtin_amdgcn_mfma_f32_16x16x32_bf16(aT1[ks],bR[nt][ks], accR[1][nt], 0, 0, 0);
            }
        }
        // epilogue: sigmoid(edge) + res, store fp32
        #pragma unroll
        for (int mt = 0; mt < 2; ++mt)
            #pragma unroll
            for (int nt = 0; nt < 2; ++nt)
                #pragma unroll
                for (int rr = 0; rr < 4; ++rr) {
                    const int row = mt * 16 + quad * 4 + rr;
                    const int col = n0 + nt * 16 + r16;
                    const float e  = accE[mt][nt][rr];
                    const float sg = 1.f / (1.f + __expf(-e));
                    out[(jb + row) * D_ + col] = sg + accR[mt][nt][rr];
                }
    };

    // ---- main pipeline: W(next) -> barrier -> M(curr) -> tload(next) ----
    const int stride = gridDim.x;
    int bn = blockIdx.x;
    bf16x8 tf[4];
    phaseW(bn, wbuf[0]);
    tload(bn, tf);
    int buf = 0;
    for (; bn < TOT; bn += stride) {
        const int nb   = bn + stride;
        const int nbuf = (buf == 2) ? 0 : buf + 1;
        if (nb < TOT) phaseW(nb, wbuf[nbuf]);
        __syncthreads();
        phaseM(bn, wbuf[buf], tf);
        if (nb < TOT) tload(nb, tf);
        buf = nbuf;
    }
}

extern "C" void kernel_launch(void* const* d_in, const int* in_sizes, int n_in,
                              void* d_out, int out_size, void* d_ws, size_t ws_size,
                              hipStream_t stream) {
    const float* t_ij = (const float*)d_in[0];
    const float* x1   = (const float*)d_in[1];
    const float* x2   = (const float*)d_in[2];
    const int*   nidx = (const int*)  d_in[3];
    const float* Wq   = (const float*)d_in[4];
    const float* Wk1  = (const float*)d_in[5];
    const float* Wk2  = (const float*)d_in[6];
    const float* lnw  = (const float*)d_in[7];
    const float* eww  = (const float*)d_in[8];
    const float* rww  = (const float*)d_in[9];
    float* out = (float*)d_out;

    // ws layout: qws fp32 [bn][e][8] (16.78 MB) | kws bf16 [bn][e][8] (8.39 MB)
    float*  qws = (float*)d_ws;
    __bf16* kws = (__bf16*)(qws + (size_t)TOT * E_ * 8);

    proj_kernel<<<TOT / 4, 256, 0, stream>>>(x1, x2, Wq, Wk1, Wk2, qws, kws);
    fused_kernel<<<FGRID, 256, 0, stream>>>(t_ij, nidx, qws, kws, lnw, eww, rww, out);
}

// Round 5
// 370.330 us; speedup vs baseline: 1.5835x; 1.0648x over previous
//
#include <hip/hip_runtime.h>

#define B_ 2
#define N_ 4096
#define M_ 32
#define D_ 128
#define E_ 64
#define LN_EPS 1e-5f
#define WST 136              // bf16 elems/row of w-tile: 272B rows, 16B-aligned
#define TOT (B_ * N_)
#define FGRID 768            // 3 blocks/CU. Round-4 lesson: 1536 blocks = same
                             // time (shared-issue-throughput-bound, not latency)
                             // so revert to the proven residency and CUT ISSUE.

typedef __bf16 bf16x8 __attribute__((ext_vector_type(8)));
typedef float  f32x4  __attribute__((ext_vector_type(4)));

// ---------------------------------------------------------------------------
// K1: projections (unchanged, proven). One wave per bn (4 bn / 256-thr block).
// q stored fp32 [bn][e][8]; k stored bf16 [bn][e][8].
// Slots: 0..2 = x1(ml0..2), 3..7 = x2(ml0..4).
// ---------------------------------------------------------------------------
__global__ __launch_bounds__(256) void proj_kernel(
    const float* __restrict__ x1, const float* __restrict__ x2,
    const float* __restrict__ Wq, const float* __restrict__ Wk1,
    const float* __restrict__ Wk2,
    float* __restrict__ qws, __bf16* __restrict__ kws)
{
    __shared__ float xs[4][D_ * 8];
    const int lane = threadIdx.x & 63;
    const int wv   = threadIdx.x >> 6;
    const int bn   = blockIdx.x * 4 + wv;
    float* xw = xs[wv];
    const float* __restrict__ x1p = x1 + (size_t)bn * (D_ * 3);
    const float* __restrict__ x2p = x2 + (size_t)bn * (D_ * 5);
    for (int i = lane; i < D_ * 3; i += 64) xw[(i / 3) * 8 + (i % 3)]     = x1p[i];
    for (int i = lane; i < D_ * 5; i += 64) xw[(i / 5) * 8 + 3 + (i % 5)] = x2p[i];
    __syncthreads();

    float q[8] = {0.f,0.f,0.f,0.f,0.f,0.f,0.f,0.f};
    float k[8] = {0.f,0.f,0.f,0.f,0.f,0.f,0.f,0.f};
    #pragma unroll 4
    for (int d = 0; d < D_; ++d) {
        const float4 xa = *(const float4*)&xw[d * 8];       // broadcast b128
        const float4 xb = *(const float4*)&xw[d * 8 + 4];
        const float wq  = Wq [d * E_ + lane];
        const float wk1 = Wk1[d * E_ + lane];
        const float wk2 = Wk2[d * E_ + lane];
        q[0] += xa.x * wq;  q[1] += xa.y * wq;  q[2] += xa.z * wq;  q[3] += xa.w * wq;
        q[4] += xb.x * wq;  q[5] += xb.y * wq;  q[6] += xb.z * wq;  q[7] += xb.w * wq;
        k[0] += xa.x * wk1; k[1] += xa.y * wk1; k[2] += xa.z * wk1;
        k[3] += xa.w * wk2; k[4] += xb.x * wk2; k[5] += xb.y * wk2;
        k[6] += xb.z * wk2; k[7] += xb.w * wk2;
    }
    float4* qo = (float4*)(qws + ((size_t)bn * E_ + lane) * 8);
    qo[0] = make_float4(q[0], q[1], q[2], q[3]);
    qo[1] = make_float4(q[4], q[5], q[6], q[7]);
    bf16x8 kb;
    #pragma unroll
    for (int s = 0; s < 8; ++s) kb[s] = (__bf16)k[s];
    *(bf16x8*)(kws + ((size_t)bn * E_ + lane) * 8) = kb;
}

// ---------------------------------------------------------------------------
// Wave-wide sum reduction, low-issue form (round-4 lesson: kernel is
// combined-issue-bound; the old 6-level __shfl_xor burned 12 DS-pipe ops per
// row). Levels 1/2/4/8 via DPP on the VALU pipe (quad_perm xor1=0xB1,
// xor2=0x4E, row_half_mirror=0x141, row_mirror=0x140), level 16 via one
// ds_swizzle (0x401F, xor16 within each 32-half), level 32 via one shfl.
// ---------------------------------------------------------------------------
__device__ __forceinline__ float dpp_red16(float v) {
    v += __int_as_float(__builtin_amdgcn_update_dpp(0, __float_as_int(v), 0xB1,  0xF, 0xF, true));
    v += __int_as_float(__builtin_amdgcn_update_dpp(0, __float_as_int(v), 0x4E,  0xF, 0xF, true));
    v += __int_as_float(__builtin_amdgcn_update_dpp(0, __float_as_int(v), 0x141, 0xF, 0xF, true));
    v += __int_as_float(__builtin_amdgcn_update_dpp(0, __float_as_int(v), 0x140, 0xF, 0xF, true));
    return v;
}
__device__ __forceinline__ float wave_sum(float v) {
    v = dpp_red16(v);
    v += __int_as_float(__builtin_amdgcn_ds_swizzle(__float_as_int(v), 0x401F));
    v += __shfl_xor(v, 32, 64);
    return v;
}

// ---------------------------------------------------------------------------
// K2: fused gather + LN + dual MFMA matmul + epilogue.
// Skeleton identical to the proven 159us round-0 kernel. Issue-count cuts:
//   * TRANSPOSED MFMA: mfma(weightFrag, wFrag) instead of (wFrag, weightFrag).
//     A/B fragment lane layouts are symmetric, so the register contents are
//     unchanged; output comes out as C^T: thread holds 4 consecutive d at
//     fixed j -> the 16 scattered global_store_dword become 4 dwordx4.
//   * sigmoid via __builtin_amdgcn_rcpf: kills the precise-div expansion
//     (~8 instr x 16 outputs -> 2 instr x 16).
//   * LN reduction via DPP+swizzle: 96 DS-pipe shuffle ops -> 32.
// Pipeline per bn: phaseW(next) -> barrier -> phaseM(curr) -> tload(next).
// Triple buffer + single barrier race-free as before.
// ---------------------------------------------------------------------------
__global__ __launch_bounds__(256, 3) void fused_kernel(
    const float* __restrict__ t_ij, const int* __restrict__ nidx,
    const float* __restrict__ qws, const __bf16* __restrict__ kws,
    const float* __restrict__ ln_w,
    const float* __restrict__ edge_w, const float* __restrict__ res_w,
    float* __restrict__ out)
{
    __shared__ __bf16 wbuf[3][M_ * WST];

    const int t    = threadIdx.x;
    const int lane = t & 63;
    const int wvu  = t >> 6;
    const int r16  = lane & 15;
    const int quad = lane >> 4;
    const int n0   = wvu * 32;          // this wave's 32-d output slice

    // ---- persistent weight fragments (fp32 global -> bf16 regs) ----
    // Used as MFMA *A* operand now: lane holds A[d = n0+nt*16+r16][f = ks*32
    // + quad*8 + j] = edge_w[f][d] -- same elements/loads as before.
    bf16x8 bE[2][4], bR[2][4];
    #pragma unroll
    for (int nt = 0; nt < 2; ++nt) {
        const int col = n0 + nt * 16 + r16;
        #pragma unroll
        for (int ks = 0; ks < 4; ++ks) {
            const int k0 = ks * 32 + quad * 8;
            bf16x8 fe, fr;
            #pragma unroll
            for (int j = 0; j < 8; ++j) {
                fe[j] = (__bf16)edge_w[(k0 + j) * D_ + col];
                fr[j] = (__bf16)res_w [(k0 + j) * D_ + col];
            }
            bE[nt][ks] = fe;
            bR[nt][ks] = fr;
        }
    }

    const float lnlo = ln_w[lane];
    const float lnhi = ln_w[64 + lane];

    // ---- phase W: compute+LN 8 j-rows of w into an LDS buffer ----
    auto phaseW = [&](int bn, __bf16* buf) {
        const int    b  = bn >> 12;
        const size_t jb = (size_t)bn * M_;
        const float* qp = qws + ((size_t)bn * E_ + lane) * 8;
        const float4 qa = *(const float4*)qp;
        const float4 qb = *(const float4*)(qp + 4);
        #pragma unroll 4
        for (int jj = 0; jj < 8; ++jj) {
            const int j  = wvu * 8 + jj;
            const int nj = nidx[jb + j];
            const bf16x8 kv =
                *(const bf16x8*)&kws[((size_t)(b * N_ + nj) * E_ + lane) * 8];
            const float wlo = qa.x * (float)kv[0] + qa.y * (float)kv[1]
                            + qa.z * (float)kv[2];
            const float whi = qa.w * (float)kv[3] + qb.x * (float)kv[4]
                            + qb.y * (float)kv[5] + qb.z * (float)kv[6]
                            + qb.w * (float)kv[7];
            const float s1 = wave_sum(wlo + whi);
            const float s2 = wave_sum(wlo * wlo + whi * whi);
            const float mu  = s1 * (1.f / 128.f);
            const float var = fmaxf(s2 * (1.f / 128.f) - mu * mu, 0.f);
            const float rs  = rsqrtf(var + LN_EPS);
            buf[j * WST + lane]      = (__bf16)((wlo - mu) * rs * lnlo);
            buf[j * WST + 64 + lane] = (__bf16)((whi - mu) * rs * lnhi);
        }
    };

    // ---- t_ij prefetch for mt=0 rows (r16), packed to bf16 B-frags ----
    auto tload = [&](int bn, bf16x8* tf) {
        const float* tp = t_ij + ((size_t)bn * M_ + r16) * D_;
        #pragma unroll
        for (int ks = 0; ks < 4; ++ks) {
            const int ko = ks * 32 + quad * 8;
            const float4 t0 = *(const float4*)(tp + ko);
            const float4 t1 = *(const float4*)(tp + ko + 4);
            bf16x8 a;
            a[0]=(__bf16)t0.x; a[1]=(__bf16)t0.y; a[2]=(__bf16)t0.z; a[3]=(__bf16)t0.w;
            a[4]=(__bf16)t1.x; a[5]=(__bf16)t1.y; a[6]=(__bf16)t1.z; a[7]=(__bf16)t1.w;
            tf[ks] = a;
        }
    };

    // ---- phase M: transposed dual matmul + fused epilogue ----
    auto phaseM = [&](int bn, const __bf16* buf, const bf16x8* tf) {
        const size_t jb = (size_t)bn * M_;
        // mt=1 t_ij rows: load + convert immediately (keeps VGPR low)
        bf16x8 aT1[4];
        {
            const float* tp = t_ij + (jb + 16 + r16) * D_;
            #pragma unroll
            for (int ks = 0; ks < 4; ++ks) {
                const int ko = ks * 32 + quad * 8;
                const float4 t0 = *(const float4*)(tp + ko);
                const float4 t1 = *(const float4*)(tp + ko + 4);
                bf16x8 a;
                a[0]=(__bf16)t0.x; a[1]=(__bf16)t0.y; a[2]=(__bf16)t0.z; a[3]=(__bf16)t0.w;
                a[4]=(__bf16)t1.x; a[5]=(__bf16)t1.y; a[6]=(__bf16)t1.z; a[7]=(__bf16)t1.w;
                aT1[ks] = a;
            }
        }
        f32x4 accE[2][2], accR[2][2];   // [mt = j-block][nt = d-block]
        #pragma unroll
        for (int mt = 0; mt < 2; ++mt)
            #pragma unroll
            for (int nt = 0; nt < 2; ++nt) {
                accE[mt][nt] = (f32x4){0.f,0.f,0.f,0.f};
                accR[mt][nt] = (f32x4){0.f,0.f,0.f,0.f};
            }
        #pragma unroll
        for (int ks = 0; ks < 4; ++ks) {
            const bf16x8 aW0 = *(const bf16x8*)&buf[r16 * WST + ks * 32 + quad * 8];
            const bf16x8 aW1 = *(const bf16x8*)&buf[(16 + r16) * WST + ks * 32 + quad * 8];
            #pragma unroll
            for (int nt = 0; nt < 2; ++nt) {
                // D = A*B with A = weights (d rows), B = w / t (j cols): C^T
                accE[0][nt] = __builtin_amdgcn_mfma_f32_16x16x32_bf16(bE[nt][ks], aW0,     accE[0][nt], 0, 0, 0);
                accR[0][nt] = __builtin_amdgcn_mfma_f32_16x16x32_bf16(bR[nt][ks], tf[ks],  accR[0][nt], 0, 0, 0);
                accE[1][nt] = __builtin_amdgcn_mfma_f32_16x16x32_bf16(bE[nt][ks], aW1,     accE[1][nt], 0, 0, 0);
                accR[1][nt] = __builtin_amdgcn_mfma_f32_16x16x32_bf16(bR[nt][ks], aT1[ks], accR[1][nt], 0, 0, 0);
            }
        }
        // epilogue: sigmoid(edge) + res. Thread holds j = mt*16+r16 fixed,
        // d = n0 + nt*16 + quad*4 + rr -> 4 contiguous floats -> dwordx4.
        #pragma unroll
        for (int mt = 0; mt < 2; ++mt)
            #pragma unroll
            for (int nt = 0; nt < 2; ++nt) {
                float4 o;
                #pragma unroll
                for (int rr = 0; rr < 4; ++rr) {
                    const float e  = accE[mt][nt][rr];
                    const float sg = __builtin_amdgcn_rcpf(1.f + __expf(-e));
                    (&o.x)[rr] = sg + accR[mt][nt][rr];
                }
                *(float4*)(out + (jb + mt * 16 + r16) * D_ + n0 + nt * 16 + quad * 4) = o;
            }
    };

    // ---- main pipeline: W(next) -> barrier -> M(curr) -> tload(next) ----
    const int stride = gridDim.x;
    int bn = blockIdx.x;
    bf16x8 tf[4];
    phaseW(bn, wbuf[0]);
    tload(bn, tf);
    int buf = 0;
    for (; bn < TOT; bn += stride) {
        const int nb   = bn + stride;
        const int nbuf = (buf == 2) ? 0 : buf + 1;
        if (nb < TOT) phaseW(nb, wbuf[nbuf]);
        __syncthreads();
        phaseM(bn, wbuf[buf], tf);
        if (nb < TOT) tload(nb, tf);
        buf = nbuf;
    }
}

extern "C" void kernel_launch(void* const* d_in, const int* in_sizes, int n_in,
                              void* d_out, int out_size, void* d_ws, size_t ws_size,
                              hipStream_t stream) {
    const float* t_ij = (const float*)d_in[0];
    const float* x1   = (const float*)d_in[1];
    const float* x2   = (const float*)d_in[2];
    const int*   nidx = (const int*)  d_in[3];
    const float* Wq   = (const float*)d_in[4];
    const float* Wk1  = (const float*)d_in[5];
    const float* Wk2  = (const float*)d_in[6];
    const float* lnw  = (const float*)d_in[7];
    const float* eww  = (const float*)d_in[8];
    const float* rww  = (const float*)d_in[9];
    float* out = (float*)d_out;

    // ws layout: qws fp32 [bn][e][8] (16.78 MB) | kws bf16 [bn][e][8] (8.39 MB)
    float*  qws = (float*)d_ws;
    __bf16* kws = (__bf16*)(qws + (size_t)TOT * E_ * 8);

    proj_kernel<<<TOT / 4, 256, 0, stream>>>(x1, x2, Wq, Wk1, Wk2, qws, kws);
    fused_kernel<<<FGRID, 256, 0, stream>>>(t_ij, nidx, qws, kws, lnw, eww, rww, out);
}

// Round 6
// 348.674 us; speedup vs baseline: 1.6818x; 1.0621x over previous
//
#include <hip/hip_runtime.h>

#define B_ 2
#define N_ 4096
#define M_ 32
#define D_ 128
#define E_ 64
#define LN_EPS 1e-5f
#define WST 136              // bf16 elems/row of a tile row: 272B, 16B-aligned
#define TOT (B_ * N_)
#define FGRID 768            // 3 blocks/CU (LDS 52.2KB x3 = 156.7/160KB)

typedef __bf16 bf16x8 __attribute__((ext_vector_type(8)));
typedef __bf16 bf16x2 __attribute__((ext_vector_type(2)));
typedef float  f32x4  __attribute__((ext_vector_type(4)));

// ---------------------------------------------------------------------------
// K1: projections (unchanged, proven). One wave per bn (4 bn / 256-thr block).
// q stored fp32 [bn][e][8]; k stored bf16 [bn][e][8].
// Slots: 0..2 = x1(ml0..2), 3..7 = x2(ml0..4).
// ---------------------------------------------------------------------------
__global__ __launch_bounds__(256) void proj_kernel(
    const float* __restrict__ x1, const float* __restrict__ x2,
    const float* __restrict__ Wq, const float* __restrict__ Wk1,
    const float* __restrict__ Wk2,
    float* __restrict__ qws, __bf16* __restrict__ kws)
{
    __shared__ float xs[4][D_ * 8];
    const int lane = threadIdx.x & 63;
    const int wv   = threadIdx.x >> 6;
    const int bn   = blockIdx.x * 4 + wv;
    float* xw = xs[wv];
    const float* __restrict__ x1p = x1 + (size_t)bn * (D_ * 3);
    const float* __restrict__ x2p = x2 + (size_t)bn * (D_ * 5);
    for (int i = lane; i < D_ * 3; i += 64) xw[(i / 3) * 8 + (i % 3)]     = x1p[i];
    for (int i = lane; i < D_ * 5; i += 64) xw[(i / 5) * 8 + 3 + (i % 5)] = x2p[i];
    __syncthreads();

    float q[8] = {0.f,0.f,0.f,0.f,0.f,0.f,0.f,0.f};
    float k[8] = {0.f,0.f,0.f,0.f,0.f,0.f,0.f,0.f};
    #pragma unroll 4
    for (int d = 0; d < D_; ++d) {
        const float4 xa = *(const float4*)&xw[d * 8];       // broadcast b128
        const float4 xb = *(const float4*)&xw[d * 8 + 4];
        const float wq  = Wq [d * E_ + lane];
        const float wk1 = Wk1[d * E_ + lane];
        const float wk2 = Wk2[d * E_ + lane];
        q[0] += xa.x * wq;  q[1] += xa.y * wq;  q[2] += xa.z * wq;  q[3] += xa.w * wq;
        q[4] += xb.x * wq;  q[5] += xb.y * wq;  q[6] += xb.z * wq;  q[7] += xb.w * wq;
        k[0] += xa.x * wk1; k[1] += xa.y * wk1; k[2] += xa.z * wk1;
        k[3] += xa.w * wk2; k[4] += xb.x * wk2; k[5] += xb.y * wk2;
        k[6] += xb.z * wk2; k[7] += xb.w * wk2;
    }
    float4* qo = (float4*)(qws + ((size_t)bn * E_ + lane) * 8);
    qo[0] = make_float4(q[0], q[1], q[2], q[3]);
    qo[1] = make_float4(q[4], q[5], q[6], q[7]);
    bf16x8 kb;
    #pragma unroll
    for (int s = 0; s < 8; ++s) kb[s] = (__bf16)k[s];
    *(bf16x8*)(kws + ((size_t)bn * E_ + lane) * 8) = kb;
}

// ---------------------------------------------------------------------------
// Wave-wide sum: DPP for levels 1/2/4/8 (VALU pipe), ds_swizzle xor16,
// shfl for xor32. Proven in round 5.
// ---------------------------------------------------------------------------
__device__ __forceinline__ float dpp_red16(float v) {
    v += __int_as_float(__builtin_amdgcn_update_dpp(0, __float_as_int(v), 0xB1,  0xF, 0xF, true));
    v += __int_as_float(__builtin_amdgcn_update_dpp(0, __float_as_int(v), 0x4E,  0xF, 0xF, true));
    v += __int_as_float(__builtin_amdgcn_update_dpp(0, __float_as_int(v), 0x141, 0xF, 0xF, true));
    v += __int_as_float(__builtin_amdgcn_update_dpp(0, __float_as_int(v), 0x140, 0xF, 0xF, true));
    return v;
}
__device__ __forceinline__ float wave_sum(float v) {
    v = dpp_red16(v);
    v += __int_as_float(__builtin_amdgcn_ds_swizzle(__float_as_int(v), 0x401F));
    v += __shfl_xor(v, 32, 64);
    return v;
}

// ---------------------------------------------------------------------------
// K2: fused gather + LN + dual MFMA matmul + epilogue.
// Round-6 changes (targets: redundant issue + L1 traffic + gather latency):
//   * t_ij staged ONCE per block into LDS bf16 (was 4x redundant per-wave
//     load+convert): stageT converts only 1/4 per wave; phaseM reads t
//     B-frags via ds_read_b128 like the w-tile. -12 VMEM, -80 VALU per wave.
//   * w-tile k-dim INTERLEAVED (k'=2e -> w_lo(e), 2e+1 -> w_hi(e)): lane
//     writes one packed b32 instead of two b16s. bE fragment loads use the
//     same permutation (k-sum invariant). LN weights applied pre-pack.
//   * phaseW fully unrolled: all 8 nidx->gather chains batched (1 latency
//     level, was 2). VGPR cap 168 at 3 waves/SIMD absorbs the live kv[8].
//   * nontemporal t_ij loads + out stores: 268MB of stream-once traffic no
//     longer evicts the kws/qws working set from L2.
// LDS: 3 slots x (w 32x136 + t 32x136) bf16 = 52224 B -> still 3 blocks/CU.
// Same triple-buffer single-barrier rotation (write slot s_{i+1} at iter i
// post-barrier_{i-1}; last read of it was phaseM(i-2) pre-barrier_{i-1}).
// ---------------------------------------------------------------------------
__global__ __launch_bounds__(256, 3) void fused_kernel(
    const float* __restrict__ t_ij, const int* __restrict__ nidx,
    const float* __restrict__ qws, const __bf16* __restrict__ kws,
    const float* __restrict__ ln_w,
    const float* __restrict__ edge_w, const float* __restrict__ res_w,
    float* __restrict__ out)
{
    __shared__ __bf16 sbuf[3][2][M_ * WST];   // [slot][0 = w-tile, 1 = t-tile]

    const int t    = threadIdx.x;
    const int lane = t & 63;
    const int wvu  = t >> 6;
    const int r16  = lane & 15;
    const int quad = lane >> 4;
    const int n0   = wvu * 32;          // this wave's 32-d output slice

    // ---- persistent weight fragments (fp32 global -> bf16 regs) ----
    // A-operand of the transposed MFMA. bE uses the interleaved k-layout:
    // stored k' holds feature f = (k'&1) ? 64+(k'>>1) : (k'>>1).
    bf16x8 bE[2][4], bR[2][4];
    #pragma unroll
    for (int nt = 0; nt < 2; ++nt) {
        const int col = n0 + nt * 16 + r16;
        #pragma unroll
        for (int ks = 0; ks < 4; ++ks) {
            const int k0 = ks * 32 + quad * 8;
            bf16x8 fe, fr;
            #pragma unroll
            for (int j = 0; j < 8; ++j) {
                const int kk = k0 + j;
                const int f  = (kk & 1) ? 64 + (kk >> 1) : (kk >> 1);
                fe[j] = (__bf16)edge_w[f * D_ + col];
                fr[j] = (__bf16)res_w [kk * D_ + col];
            }
            bE[nt][ks] = fe;
            bR[nt][ks] = fr;
        }
    }

    const float lnlo = ln_w[lane];
    const float lnhi = ln_w[64 + lane];

    // ---- phase W: gather + inner products + LN, packed b32 writes ----
    auto phaseW = [&](int bn, __bf16* wb) {
        const int    b  = bn >> 12;
        const size_t jb = (size_t)bn * M_;
        const float* qp = qws + ((size_t)bn * E_ + lane) * 8;
        const float4 qa = *(const float4*)qp;
        const float4 qb = *(const float4*)(qp + 4);
        #pragma unroll
        for (int jj = 0; jj < 8; ++jj) {
            const int j  = wvu * 8 + jj;
            const int nj = nidx[jb + j];
            const bf16x8 kv =
                *(const bf16x8*)&kws[((size_t)(b * N_ + nj) * E_ + lane) * 8];
            const float wlo = qa.x * (float)kv[0] + qa.y * (float)kv[1]
                            + qa.z * (float)kv[2];
            const float whi = qa.w * (float)kv[3] + qb.x * (float)kv[4]
                            + qb.y * (float)kv[5] + qb.z * (float)kv[6]
                            + qb.w * (float)kv[7];
            const float s1 = wave_sum(wlo + whi);
            const float s2 = wave_sum(wlo * wlo + whi * whi);
            const float mu  = s1 * (1.f / 128.f);
            const float var = fmaxf(s2 * (1.f / 128.f) - mu * mu, 0.f);
            const float rs  = rsqrtf(var + LN_EPS);
            bf16x2 p;
            p[0] = (__bf16)((wlo - mu) * rs * lnlo);
            p[1] = (__bf16)((whi - mu) * rs * lnhi);
            *(bf16x2*)&wb[j * WST + 2 * lane] = p;   // one b32 write
        }
    };

    // ---- stage T: cooperative t_ij -> bf16 LDS tile (rows = j, cols = d).
    // Wave wvu converts rows wvu*8..+8; lane handles 16 consecutive floats.
    auto stageT = [&](int bn, __bf16* tb) {
        const int row = wvu * 8 + (lane >> 3);
        const int c0  = (lane & 7) * 16;
        const float* tp = t_ij + ((size_t)bn * M_ + row) * D_ + c0;
        const f32x4 t0 = __builtin_nontemporal_load((const f32x4*)tp);
        const f32x4 t1 = __builtin_nontemporal_load((const f32x4*)(tp + 4));
        const f32x4 t2 = __builtin_nontemporal_load((const f32x4*)(tp + 8));
        const f32x4 t3 = __builtin_nontemporal_load((const f32x4*)(tp + 12));
        bf16x8 a0, a1;
        #pragma unroll
        for (int r = 0; r < 4; ++r) {
            a0[r]     = (__bf16)t0[r];
            a0[4 + r] = (__bf16)t1[r];
            a1[r]     = (__bf16)t2[r];
            a1[4 + r] = (__bf16)t3[r];
        }
        *(bf16x8*)&tb[row * WST + c0]     = a0;
        *(bf16x8*)&tb[row * WST + c0 + 8] = a1;
    };

    // ---- phase M: all operands from LDS/regs; dual matmul + epilogue ----
    auto phaseM = [&](int bn, const __bf16* wb, const __bf16* tb) {
        const size_t jb = (size_t)bn * M_;
        f32x4 accE[2][2], accR[2][2];   // [mt = j-block][nt = d-block]
        #pragma unroll
        for (int mt = 0; mt < 2; ++mt)
            #pragma unroll
            for (int nt = 0; nt < 2; ++nt) {
                accE[mt][nt] = (f32x4){0.f,0.f,0.f,0.f};
                accR[mt][nt] = (f32x4){0.f,0.f,0.f,0.f};
            }
        #pragma unroll
        for (int ks = 0; ks < 4; ++ks) {
            const int off = ks * 32 + quad * 8;
            const bf16x8 aW0 = *(const bf16x8*)&wb[r16 * WST + off];
            const bf16x8 aW1 = *(const bf16x8*)&wb[(16 + r16) * WST + off];
            const bf16x8 tW0 = *(const bf16x8*)&tb[r16 * WST + off];
            const bf16x8 tW1 = *(const bf16x8*)&tb[(16 + r16) * WST + off];
            #pragma unroll
            for (int nt = 0; nt < 2; ++nt) {
                accE[0][nt] = __builtin_amdgcn_mfma_f32_16x16x32_bf16(bE[nt][ks], aW0, accE[0][nt], 0, 0, 0);
                accR[0][nt] = __builtin_amdgcn_mfma_f32_16x16x32_bf16(bR[nt][ks], tW0, accR[0][nt], 0, 0, 0);
                accE[1][nt] = __builtin_amdgcn_mfma_f32_16x16x32_bf16(bE[nt][ks], aW1, accE[1][nt], 0, 0, 0);
                accR[1][nt] = __builtin_amdgcn_mfma_f32_16x16x32_bf16(bR[nt][ks], tW1, accR[1][nt], 0, 0, 0);
            }
        }
        // epilogue: sigmoid(edge) + res; thread holds j fixed, 4 contiguous d
        #pragma unroll
        for (int mt = 0; mt < 2; ++mt)
            #pragma unroll
            for (int nt = 0; nt < 2; ++nt) {
                f32x4 o;
                #pragma unroll
                for (int rr = 0; rr < 4; ++rr) {
                    const float e  = accE[mt][nt][rr];
                    const float sg = __builtin_amdgcn_rcpf(1.f + __expf(-e));
                    o[rr] = sg + accR[mt][nt][rr];
                }
                __builtin_nontemporal_store(o,
                    (f32x4*)(out + (jb + mt * 16 + r16) * D_ + n0 + nt * 16 + quad * 4));
            }
    };

    // ---- main pipeline: stage(next) -> barrier -> M(curr) ----
    const int stride = gridDim.x;
    int bn = blockIdx.x;
    phaseW(bn, sbuf[0][0]);
    stageT(bn, sbuf[0][1]);
    int buf = 0;
    for (; bn < TOT; bn += stride) {
        const int nb   = bn + stride;
        const int nbuf = (buf == 2) ? 0 : buf + 1;
        if (nb < TOT) {
            phaseW(nb, sbuf[nbuf][0]);
            stageT(nb, sbuf[nbuf][1]);
        }
        __syncthreads();
        phaseM(bn, sbuf[buf][0], sbuf[buf][1]);
        buf = nbuf;
    }
}

extern "C" void kernel_launch(void* const* d_in, const int* in_sizes, int n_in,
                              void* d_out, int out_size, void* d_ws, size_t ws_size,
                              hipStream_t stream) {
    const float* t_ij = (const float*)d_in[0];
    const float* x1   = (const float*)d_in[1];
    const float* x2   = (const float*)d_in[2];
    const int*   nidx = (const int*)  d_in[3];
    const float* Wq   = (const float*)d_in[4];
    const float* Wk1  = (const float*)d_in[5];
    const float* Wk2  = (const float*)d_in[6];
    const float* lnw  = (const float*)d_in[7];
    const float* eww  = (const float*)d_in[8];
    const float* rww  = (const float*)d_in[9];
    float* out = (float*)d_out;

    // ws layout: qws fp32 [bn][e][8] (16.78 MB) | kws bf16 [bn][e][8] (8.39 MB)
    float*  qws = (float*)d_ws;
    __bf16* kws = (__bf16*)(qws + (size_t)TOT * E_ * 8);

    proj_kernel<<<TOT / 4, 256, 0, stream>>>(x1, x2, Wq, Wk1, Wk2, qws, kws);
    fused_kernel<<<FGRID, 256, 0, stream>>>(t_ij, nidx, qws, kws, lnw, eww, rww, out);
}